// Round 3
// baseline (61.932 us; speedup 1.0000x reference)
//
#include <hip/hip_runtime.h>

// Path signature, depth 4, D=8. Output layout (matches JAX flatten):
//   s1[8] | s2[64] (i*8+j) | s3[512] (i*64+j*8+k) | s4[4096] (i*512+j*64+k*8+l)
//
// Single fused kernel, 256 blocks:
//   phase 1: every block computes the signature of its 32-increment chunk
//            (state fully thread-private in registers, barrier-free loop)
//   phase 2: blocks 0..15 fold 16 chunk signatures each (Chen product)
//   phase 3: block 0 folds the 16 group results into d_out
// Cross-block handoff: device-scope release (__threadfence + agent atomic
// store MAGIC) / acquire (agent atomic load + __threadfence) flags in d_ws.
// Flags are reset to 0 by block 0 at the end so graph replays see a clean
// state (first call sees harness poison 0xAAAAAAAA != MAGIC, also fine).
#define SIGLEN 4680
#define S1OFF 0
#define S2OFF 8
#define S3OFF 72
#define S4OFF 584
#define NCHUNK 256
#define NG 16
#define MAGIC 0x13572468u
#define MAXLEN 128  // max increments per chunk staged in LDS

struct SigRegs {
  float s4[16];
  float a1, a2, a30, a31;
};

// Full Chen left-fold: A (registers) <- A * B (memory).
//   c4 = a4 + b4 + a1(x)b3 + a2(x)b2 + a3(x)b1
//   c3 = a3 + b3 + a1(x)b2 + a2(x)b1 ; c2 = a2 + b2 + a1(x)b1 ; c1 = a1 + b1
__device__ __forceinline__ void fold_into(SigRegs& A, const float* __restrict__ B,
                                          int i_idx, int j_idx, int k0, int t) {
  const float4 b1lo = *(const float4*)(B + S1OFF);
  const float4 b1hi = *(const float4*)(B + S1OFF + 4);
  const float b1v[8] = {b1lo.x, b1lo.y, b1lo.z, b1lo.w, b1hi.x, b1hi.y, b1hi.z, b1hi.w};
  const float b1i = B[S1OFF + i_idx];
  const float b1j = B[S1OFF + j_idx];
  const float2 b1k = *(const float2*)(B + S1OFF + k0);
  const float b2own = B[S2OFF + (t >> 2)];
  const float2 b2p = *(const float2*)(B + S2OFF + ((2 * t) & 63));
  const float2 b3p = *(const float2*)(B + S3OFF + 2 * t);
  float b2r[16], b3r[16], b4r[16];
  const float4* q2 = (const float4*)(B + S2OFF + 16 * (t & 3));
  const float4* q3 = (const float4*)(B + S3OFF + 16 * (t & 31));
  const float4* q4 = (const float4*)(B + S4OFF + 16 * t);
#pragma unroll
  for (int r = 0; r < 4; ++r) {
    const float4 v2 = q2[r], v3 = q3[r], v4 = q4[r];
    b2r[4 * r] = v2.x; b2r[4 * r + 1] = v2.y; b2r[4 * r + 2] = v2.z; b2r[4 * r + 3] = v2.w;
    b3r[4 * r] = v3.x; b3r[4 * r + 1] = v3.y; b3r[4 * r + 2] = v3.z; b3r[4 * r + 3] = v3.w;
    b4r[4 * r] = v4.x; b4r[4 * r + 1] = v4.y; b4r[4 * r + 2] = v4.z; b4r[4 * r + 3] = v4.w;
  }
#pragma unroll
  for (int e = 0; e < 16; ++e) {
    const float a3v = (e < 8) ? A.a30 : A.a31;
    A.s4[e] += b4r[e] + A.a1 * b3r[e] + A.a2 * b2r[e] + a3v * b1v[e & 7];
  }
  A.a30 += b3p.x + A.a1 * b2p.x + A.a2 * b1k.x;
  A.a31 += b3p.y + A.a1 * b2p.y + A.a2 * b1k.y;
  A.a2 += b2own + A.a1 * b1j;
  A.a1 += b1i;
}

__device__ __forceinline__ void load_sig(SigRegs& A, const float* __restrict__ B,
                                         int i_idx, int t) {
  const float4* p4 = (const float4*)(B + S4OFF + 16 * t);
#pragma unroll
  for (int r = 0; r < 4; ++r) {
    const float4 v = p4[r];
    A.s4[4 * r] = v.x; A.s4[4 * r + 1] = v.y; A.s4[4 * r + 2] = v.z; A.s4[4 * r + 3] = v.w;
  }
  A.a1 = B[S1OFF + i_idx];
  A.a2 = B[S2OFF + (t >> 2)];
  const float2 a3i = *(const float2*)(B + S3OFF + 2 * t);
  A.a30 = a3i.x; A.a31 = a3i.y;
}

__device__ __forceinline__ void store_sig(const SigRegs& A, float* __restrict__ o,
                                          int i_idx, int t) {
  if ((t & 31) == 0) o[S1OFF + i_idx] = A.a1;
  if ((t & 3) == 0) o[S2OFF + (t >> 2)] = A.a2;
  *(float2*)(o + S3OFF + 2 * t) = make_float2(A.a30, A.a31);
  float4* o4 = (float4*)(o + S4OFF + 16 * t);
#pragma unroll
  for (int r = 0; r < 4; ++r)
    o4[r] = make_float4(A.s4[4 * r], A.s4[4 * r + 1], A.s4[4 * r + 2], A.s4[4 * r + 3]);
}

__device__ __forceinline__ void wait_flag(unsigned* f) {
  // bounded spin (safety net against protocol bugs; never hit in practice)
  for (long i = 0; i < 200000000L; ++i) {
    if (__hip_atomic_load(f, __ATOMIC_ACQUIRE, __HIP_MEMORY_SCOPE_AGENT) == MAGIC)
      return;
  }
}

__global__ __launch_bounds__(256) void sig_fused(const float* __restrict__ path,
                                                 float* __restrict__ out,
                                                 float* __restrict__ ws,
                                                 int nInc) {
  float* partials = ws;                                  // NCHUNK * SIGLEN
  float* g2 = ws + (long)NCHUNK * SIGLEN;                // NG * SIGLEN
  unsigned* cflag = (unsigned*)(g2 + (long)NG * SIGLEN); // NCHUNK
  unsigned* gflag = cflag + NCHUNK;                      // NG

  const int t = threadIdx.x;
  const int c = blockIdx.x;
  const int i_idx = t >> 5;
  const int j_idx = (t >> 2) & 7;
  const int k0 = 2 * (t & 3);

  // ---------------- phase 1: chunk signature ----------------
  __shared__ float4 pl[(MAXLEN + 1) * 2];
  __shared__ float4 dv[MAXLEN * 2];
  const long start = ((long)c * nInc) / NCHUNK;
  const long end = ((long)(c + 1) * nInc) / NCHUNK;
  const int len = (int)(end - start);

  const float4* gp = (const float4*)(path + start * 8);
  for (int idx = t; idx < (len + 1) * 2; idx += 256) pl[idx] = gp[idx];
  __syncthreads();
  for (int idx = t; idx < len * 2; idx += 256) {
    float4 a = pl[idx + 2], b = pl[idx];
    dv[idx] = make_float4(a.x - b.x, a.y - b.y, a.z - b.z, a.w - b.w);
  }
  __syncthreads();
  const float* dvf = (const float*)dv;

  SigRegs A;
#pragma unroll
  for (int e = 0; e < 16; ++e) A.s4[e] = 0.f;
  A.a1 = 0.f; A.a2 = 0.f; A.a30 = 0.f; A.a31 = 0.f;

  for (int it = 0; it < len; ++it) {
    const float4 d0 = dv[it * 2], d1 = dv[it * 2 + 1];
    const float dxl[8] = {d0.x, d0.y, d0.z, d0.w, d1.x, d1.y, d1.z, d1.w};
    const float dxi = dvf[it * 8 + i_idx];
    const float dxj = dvf[it * 8 + j_idx];
    const float2 dkk = *(const float2*)(dvf + it * 8 + k0);

    const float inner = 0.5f * A.a2 + dxj * ((1.f / 6.f) * A.a1 + (1.f / 24.f) * dxi);
    const float c0 = A.a30 + dkk.x * inner;
    const float c1 = A.a31 + dkk.y * inner;
#pragma unroll
    for (int l = 0; l < 8; ++l) A.s4[l] += c0 * dxl[l];
#pragma unroll
    for (int l = 0; l < 8; ++l) A.s4[8 + l] += c1 * dxl[l];
    const float common3 = A.a2 + dxj * (0.5f * A.a1 + (1.f / 6.f) * dxi);
    A.a30 += common3 * dkk.x;
    A.a31 += common3 * dkk.y;
    A.a2 += dxj * (A.a1 + 0.5f * dxi);
    A.a1 += dxi;
  }

  store_sig(A, partials + (long)c * SIGLEN, i_idx, t);
  __syncthreads();  // all stores of this block's partial issued
  if (t == 0) {
    __threadfence();  // device-scope release of partial data
    __hip_atomic_store(&cflag[c], MAGIC, __ATOMIC_RELEASE, __HIP_MEMORY_SCOPE_AGENT);
  }
  if (c >= NG) return;

  // ---------------- phase 2: fold 16 chunk sigs (blocks 0..15) ----------------
  if (t < 16) wait_flag(&cflag[NG * c + t]);
  __syncthreads();
  __threadfence();  // acquire: invalidate caches before reading other XCDs' data

  const float* base = partials + (long)(NG * c) * SIGLEN;
  SigRegs G;
  load_sig(G, base, i_idx, t);
#pragma unroll 2
  for (int m = 1; m < NG; ++m)
    fold_into(G, base + (long)m * SIGLEN, i_idx, j_idx, k0, t);

  store_sig(G, g2 + (long)c * SIGLEN, i_idx, t);
  __syncthreads();
  if (t == 0) {
    __threadfence();
    __hip_atomic_store(&gflag[c], MAGIC, __ATOMIC_RELEASE, __HIP_MEMORY_SCOPE_AGENT);
  }
  if (c != 0) return;

  // ---------------- phase 3: fold 16 group sigs (block 0) ----------------
  if (t < 16) wait_flag(&gflag[t]);
  __syncthreads();
  __threadfence();

  SigRegs F;
  load_sig(F, g2, i_idx, t);
#pragma unroll 2
  for (int m = 1; m < NG; ++m)
    fold_into(F, g2 + (long)m * SIGLEN, i_idx, j_idx, k0, t);

  store_sig(F, out, i_idx, t);

  // reset flags for the next graph replay (safe: everything above is done,
  // and replays are serialized on the stream / kernel boundary flushes caches)
  __syncthreads();
  for (int idx = t; idx < NCHUNK; idx += 256) cflag[idx] = 0u;
  if (t < NG) gflag[t] = 0u;
}

extern "C" void kernel_launch(void* const* d_in, const int* in_sizes, int n_in,
                              void* d_out, int out_size, void* d_ws, size_t ws_size,
                              hipStream_t stream) {
  const float* path = (const float*)d_in[0];
  float* out = (float*)d_out;
  const int L = in_sizes[0] / 8;
  const int nInc = L - 1;
  sig_fused<<<NCHUNK, 256, 0, stream>>>(path, out, (float*)d_ws, nInc);
}